// Round 1
// baseline (1868.700 us; speedup 1.0000x reference)
//
#include <hip/hip_runtime.h>
#include <cstdint>
#include <cstddef>

#define T_DIM 4096
#define B_DIM 32
#define D_DIM 512
#define H_DIM 256
#define G_DIM 1024  // 4*H

typedef _Float16 h2 __attribute__((ext_vector_type(2)));
typedef _Float16 h8 __attribute__((ext_vector_type(8)));
typedef float f4 __attribute__((ext_vector_type(4)));

// ---------------------------------------------------------------------------
// Kernel A: per-batch segment extraction. A segment starts at t==0 or where
// reset[t,b]==1 (state is zeroed entering that step). Block b compacts the
// ordered start list for batch column b.
// ---------------------------------------------------------------------------
__global__ void seg_build_kernel(const int* __restrict__ reset,
                                 unsigned* __restrict__ starts,
                                 unsigned* __restrict__ segcnt) {
  __shared__ unsigned cnts[256];
  __shared__ unsigned offs[256];
  const int b = blockIdx.x;
  const int tid = threadIdx.x;
  const int t0 = tid * 16;
  unsigned c = 0;
  for (int e = 0; e < 16; ++e) {
    int t = t0 + e;
    bool pred = (t == 0) || (reset[t * B_DIM + b] != 0);
    c += pred ? 1u : 0u;
  }
  cnts[tid] = c;
  __syncthreads();
  if (tid == 0) {
    unsigned run = 0;
    for (int i = 0; i < 256; ++i) { unsigned v = cnts[i]; offs[i] = run; run += v; }
    segcnt[b] = run;
  }
  __syncthreads();
  unsigned o = (unsigned)b * 4096u + offs[tid];
  for (int e = 0; e < 16; ++e) {
    int t = t0 + e;
    bool pred = (t == 0) || (reset[t * B_DIM + b] != 0);
    if (pred) { starts[o++] = (unsigned)t; }
  }
}

// ---------------------------------------------------------------------------
// Kernel B: xw = x @ W_ih^T + b_ih + b_hh, output f16 [T*B, 1024].
// 128x128x32 tile, f16 MFMA 16x16x32, f32->f16 conversion during staging.
// grid.x = N tiles (8) fastest so A-tiles get L2 reuse across N.
// ---------------------------------------------------------------------------
#define BM 128
#define BN 128
#define BK 32

__global__ __launch_bounds__(256) void xw_gemm_kernel(
    const float* __restrict__ X, const float* __restrict__ Wih,
    const float* __restrict__ bih, const float* __restrict__ bhh,
    _Float16* __restrict__ xw) {
  __shared__ _Float16 As[BM * BK];
  __shared__ _Float16 Bs[BN * BK];
  const int tid = threadIdx.x;
  const int lane = tid & 63;
  const int wave = tid >> 6;
  const size_t m0 = (size_t)blockIdx.y * BM;
  const int n0 = blockIdx.x * BN;
  const int wm = (wave & 1) * 64;   // wave tile 64x64
  const int wn = (wave >> 1) * 64;
  const int q = lane >> 4;          // quad 0..3
  const int r = lane & 15;

  f4 acc[4][4];
#pragma unroll
  for (int i = 0; i < 4; ++i) {
#pragma unroll
    for (int j = 0; j < 4; ++j) { f4 z = {0.f, 0.f, 0.f, 0.f}; acc[i][j] = z; }
  }

  const int srow = tid >> 1;
  const int kh = (tid & 1) * 16;

  for (int k0 = 0; k0 < D_DIM; k0 += BK) {
    const float* ax = X + (m0 + (size_t)srow) * D_DIM + k0 + kh;
    const float* bx = Wih + ((size_t)(n0 + srow)) * D_DIM + k0 + kh;
    f4 a0 = *(const f4*)(ax);
    f4 a1 = *(const f4*)(ax + 4);
    f4 a2 = *(const f4*)(ax + 8);
    f4 a3 = *(const f4*)(ax + 12);
    f4 b0 = *(const f4*)(bx);
    f4 b1 = *(const f4*)(bx + 4);
    f4 b2 = *(const f4*)(bx + 8);
    f4 b3 = *(const f4*)(bx + 12);
    h8 ha0 = {(_Float16)a0.x, (_Float16)a0.y, (_Float16)a0.z, (_Float16)a0.w,
              (_Float16)a1.x, (_Float16)a1.y, (_Float16)a1.z, (_Float16)a1.w};
    h8 ha1 = {(_Float16)a2.x, (_Float16)a2.y, (_Float16)a2.z, (_Float16)a2.w,
              (_Float16)a3.x, (_Float16)a3.y, (_Float16)a3.z, (_Float16)a3.w};
    h8 hb0 = {(_Float16)b0.x, (_Float16)b0.y, (_Float16)b0.z, (_Float16)b0.w,
              (_Float16)b1.x, (_Float16)b1.y, (_Float16)b1.z, (_Float16)b1.w};
    h8 hb1 = {(_Float16)b2.x, (_Float16)b2.y, (_Float16)b2.z, (_Float16)b2.w,
              (_Float16)b3.x, (_Float16)b3.y, (_Float16)b3.z, (_Float16)b3.w};
    *(h8*)(As + srow * BK + kh) = ha0;
    *(h8*)(As + srow * BK + kh + 8) = ha1;
    *(h8*)(Bs + srow * BK + kh) = hb0;
    *(h8*)(Bs + srow * BK + kh + 8) = hb1;
    __syncthreads();

    h8 af[4], bf[4];
#pragma unroll
    for (int mi = 0; mi < 4; ++mi)
      af[mi] = *(const h8*)(As + (wm + mi * 16 + r) * BK + q * 8);
#pragma unroll
    for (int ni = 0; ni < 4; ++ni)
      bf[ni] = *(const h8*)(Bs + (wn + ni * 16 + r) * BK + q * 8);
#pragma unroll
    for (int mi = 0; mi < 4; ++mi)
#pragma unroll
      for (int ni = 0; ni < 4; ++ni)
        acc[mi][ni] = __builtin_amdgcn_mfma_f32_16x16x32_f16(af[mi], bf[ni], acc[mi][ni], 0, 0, 0);
    __syncthreads();
  }

  // C/D layout: col(n) = lane&15, row(m) = (lane>>4)*4 + reg  [m89/m91 verified]
#pragma unroll
  for (int mi = 0; mi < 4; ++mi) {
#pragma unroll
    for (int ni = 0; ni < 4; ++ni) {
      int n = n0 + wn + ni * 16 + r;
      float bias = bih[n] + bhh[n];
#pragma unroll
      for (int reg = 0; reg < 4; ++reg) {
        size_t m = m0 + (size_t)(wm + mi * 16 + q * 4 + reg);
        xw[m * G_DIM + n] = (_Float16)(acc[mi][ni][reg] + bias);
      }
    }
  }
}

// ---------------------------------------------------------------------------
// Kernel C: segment-parallel LSTM scan. 256 blocks x 1024 threads, 1 block/CU.
// Thread g owns gate row g of W_hh: k=0..191 in 96 VGPRs (f16 pairs),
// k=192..255 in LDS (128 KB, [chunk][gate][8] so reads are full-BW b128).
// h broadcast via LDS; gates -> c,h by threads 0..255; projection fused.
// ---------------------------------------------------------------------------
__device__ __forceinline__ float sigmf(float x) { return 1.f / (1.f + __expf(-x)); }
__device__ __forceinline__ float tanhf_(float x) {
  float e = __expf(-2.f * fabsf(x));
  float r = (1.f - e) / (1.f + e);
  return copysignf(r, x);
}
__device__ __forceinline__ float dot8(h8 w, h8 h, float acc) {
  acc = __builtin_amdgcn_fdot2(__builtin_shufflevector(w, w, 0, 1),
                               __builtin_shufflevector(h, h, 0, 1), acc, false);
  acc = __builtin_amdgcn_fdot2(__builtin_shufflevector(w, w, 2, 3),
                               __builtin_shufflevector(h, h, 2, 3), acc, false);
  acc = __builtin_amdgcn_fdot2(__builtin_shufflevector(w, w, 4, 5),
                               __builtin_shufflevector(h, h, 4, 5), acc, false);
  acc = __builtin_amdgcn_fdot2(__builtin_shufflevector(w, w, 6, 7),
                               __builtin_shufflevector(h, h, 6, 7), acc, false);
  return acc;
}

__global__ __launch_bounds__(1024, 1) void lstm_scan_kernel(
    const _Float16* __restrict__ xw,
    const float* __restrict__ Whh,
    const float* __restrict__ Wproj,
    const float* __restrict__ bproj,
    const unsigned* __restrict__ starts,
    const unsigned* __restrict__ segcnt,
    float* __restrict__ out) {
  __shared__ __align__(16) _Float16 wlds[8 * G_DIM * 8];  // 128 KB
  __shared__ float act[G_DIM];
  __shared__ __align__(16) _Float16 hbuf[H_DIM];
  __shared__ float partial[4];

  const int tid = threadIdx.x;
  const int b = blockIdx.x & 31;
  const int sub = blockIdx.x >> 5;

  const float* wrow = Whh + (size_t)tid * H_DIM;
  h8 wr[24];
#pragma unroll
  for (int i = 0; i < 24; ++i) {
    f4 v0 = *(const f4*)(wrow + i * 8);
    f4 v1 = *(const f4*)(wrow + i * 8 + 4);
    h8 w = {(_Float16)v0.x, (_Float16)v0.y, (_Float16)v0.z, (_Float16)v0.w,
            (_Float16)v1.x, (_Float16)v1.y, (_Float16)v1.z, (_Float16)v1.w};
    wr[i] = w;
  }
#pragma unroll
  for (int j = 0; j < 8; ++j) {
    f4 v0 = *(const f4*)(wrow + 192 + j * 8);
    f4 v1 = *(const f4*)(wrow + 192 + j * 8 + 4);
    h8 w = {(_Float16)v0.x, (_Float16)v0.y, (_Float16)v0.z, (_Float16)v0.w,
            (_Float16)v1.x, (_Float16)v1.y, (_Float16)v1.z, (_Float16)v1.w};
    *(h8*)(wlds + ((size_t)j * G_DIM + tid) * 8) = w;
  }
  const float wp = (tid < H_DIM) ? Wproj[tid] : 0.f;
  const float bp = bproj[0];
  __syncthreads();

  const h8* hb8 = (const h8*)hbuf;
  const h8* wl8 = (const h8*)wlds;
  const unsigned nseg = segcnt[b];

  for (unsigned s = sub; s < nseg; s += 8) {
    const unsigned t0 = starts[b * 4096u + s];
    const unsigned t1 = (s + 1 < nseg) ? starts[b * 4096u + s + 1] : (unsigned)T_DIM;
    float cst = 0.f;
    for (unsigned t = t0; t < t1; ++t) {
      float xv = (float)xw[((size_t)t * B_DIM + b) * G_DIM + tid];
      float accv;
      if (t == t0) {
        // first step of a segment: h == 0, recurrent term vanishes
        accv = xv;
      } else {
        float a0 = 0.f, a1 = 0.f, a2 = 0.f, a3 = 0.f;
#pragma unroll
        for (int i = 0; i < 24; i += 4) {
          a0 = dot8(wr[i], hb8[i], a0);
          a1 = dot8(wr[i + 1], hb8[i + 1], a1);
          a2 = dot8(wr[i + 2], hb8[i + 2], a2);
          a3 = dot8(wr[i + 3], hb8[i + 3], a3);
        }
        a0 = dot8(wl8[0 * G_DIM + tid], hb8[24], a0);
        a1 = dot8(wl8[1 * G_DIM + tid], hb8[25], a1);
        a2 = dot8(wl8[2 * G_DIM + tid], hb8[26], a2);
        a3 = dot8(wl8[3 * G_DIM + tid], hb8[27], a3);
        a0 = dot8(wl8[4 * G_DIM + tid], hb8[28], a0);
        a1 = dot8(wl8[5 * G_DIM + tid], hb8[29], a1);
        a2 = dot8(wl8[6 * G_DIM + tid], hb8[30], a2);
        a3 = dot8(wl8[7 * G_DIM + tid], hb8[31], a3);
        accv = ((a0 + a1) + (a2 + a3)) + xv;
      }
      act[tid] = accv;
      __syncthreads();
      if (tid < H_DIM) {
        float ai = act[tid];
        float af = act[tid + 256];
        float ag = act[tid + 512];
        float ao = act[tid + 768];
        cst = sigmf(af) * cst + sigmf(ai) * tanhf_(ag);
        float h = sigmf(ao) * tanhf_(cst);
        hbuf[tid] = (_Float16)h;
        float p = h * wp;
        p += __shfl_down(p, 32);
        p += __shfl_down(p, 16);
        p += __shfl_down(p, 8);
        p += __shfl_down(p, 4);
        p += __shfl_down(p, 2);
        p += __shfl_down(p, 1);
        if ((tid & 63) == 0) partial[tid >> 6] = p;
      }
      __syncthreads();
      if (tid == 0) {
        out[(size_t)t * B_DIM + b] = partial[0] + partial[1] + partial[2] + partial[3] + bp;
      }
      // safe: next act/partial writes are ordered behind the NEXT barrier,
      // which thread 0 only reaches after this read.
    }
  }
}

// ---------------------------------------------------------------------------
extern "C" void kernel_launch(void* const* d_in, const int* in_sizes, int n_in,
                              void* d_out, int out_size, void* d_ws, size_t ws_size,
                              hipStream_t stream) {
  const float* x = (const float*)d_in[0];
  const int* reset = (const int*)d_in[1];
  const float* Wih = (const float*)d_in[2];
  const float* Whh = (const float*)d_in[3];
  const float* bih = (const float*)d_in[4];
  const float* bhh = (const float*)d_in[5];
  const float* Wproj = (const float*)d_in[6];
  const float* bproj = (const float*)d_in[7];
  float* out = (float*)d_out;

  char* ws = (char*)d_ws;
  _Float16* xw = (_Float16*)ws;                              // 268435456 B
  unsigned* starts = (unsigned*)(ws + 268435456ULL);         // 524288 B
  unsigned* segcnt = (unsigned*)(ws + 268959744ULL);         // 128 B

  hipLaunchKernelGGL(seg_build_kernel, dim3(32), dim3(256), 0, stream,
                     reset, starts, segcnt);
  hipLaunchKernelGGL(xw_gemm_kernel, dim3(8, 1024), dim3(256), 0, stream,
                     x, Wih, bih, bhh, xw);
  hipLaunchKernelGGL(lstm_scan_kernel, dim3(256), dim3(1024), 0, stream,
                     xw, Whh, Wproj, bproj, starts, segcnt, out);
}